// Round 1
// 463.737 us; speedup vs baseline: 1.0678x; 1.0678x over previous
//
#include <hip/hip_runtime.h>
#include <math.h>

// ---------------------------------------------------------------------------
// SAGE pipeline, bf16-MFMA, round-6: branch-correlated delta-fp8 gathers.
//   Activation rows INTERLEAVED: row 2i = clean node i, row 2i+1 = noisy.
//   Layers 0/1 gather table P2: per node {128 bf16 clean | 128 fp8 delta}
//   = 384 B rows (3 cache lines, line-aligned) vs 512 B dual-bf16 before.
//   noisy_sum = clean_sum + delta_sum; |delta| <= ~0.1*||Wrow|| so fp8 e4m3
//   abs err ~3e-4..4e-3, noisy branch only, shrunk ~4x by the degree-mean.
//   FETCH was 205 MB ~= 8 XCD x 25.6 MB (L2-miss path saturated at ~4.2 TB/s
//   for random rows) -> bytes/edge is the only lever; expect ~25% cut.
//   GEMM layers 0/1 merged into ONE 512-thread dispatch (256 out cols):
//   A read once instead of twice (grid-y=2 re-read eliminated).
//   Layer 2 (47+47 cols) keeps dual-bf16 [node][2][64] rows: a 192 B delta
//   row is not line-aligned and 64 B delta slices overfetch 128 B lines.
// ---------------------------------------------------------------------------

typedef unsigned int uint;
typedef unsigned short ushort;
typedef unsigned char uchar;
typedef short bf16x8 __attribute__((ext_vector_type(8)));
typedef float f32x4 __attribute__((ext_vector_type(4)));

__device__ __forceinline__ ushort f2b(float f) {  // fp32 -> bf16 RNE
  union { float f; uint u; } v; v.f = f;
  uint u = v.u;
  return (ushort)((u + 0x7FFFu + ((u >> 16) & 1u)) >> 16);
}
__device__ __forceinline__ float b2f_lo(uint u) {
  union { uint u; float f; } v; v.u = u << 16; return v.f;
}
__device__ __forceinline__ float b2f_hi(uint u) {
  union { uint u; float f; } v; v.u = u & 0xFFFF0000u; return v.f;
}

// ---- fp8 e4m3 helpers (hardware cvt on gfx950; guarded sw fallback) -------
#if __has_builtin(__builtin_amdgcn_cvt_f32_fp8)
__device__ __forceinline__ float dec8_0(uint u) {
  return __builtin_amdgcn_cvt_f32_fp8(u, 0);
}
__device__ __forceinline__ float dec8_1(uint u) {
  return __builtin_amdgcn_cvt_f32_fp8(u, 1);
}
#else
__device__ __forceinline__ float dec8_b(uint b) {
  uint s = (b >> 7) & 1u, ex = (b >> 3) & 0xFu, m = b & 7u;
  union { uint u; float f; } v;
  if (ex == 0) {
    v.f = (float)m * 0.001953125f;  // m * 2^-9
    v.u |= s << 31;
    return v.f;
  }
  v.u = (s << 31) | ((ex + 120u) << 23) | (m << 20);
  return v.f;
}
__device__ __forceinline__ float dec8_0(uint u) { return dec8_b(u & 0xFFu); }
__device__ __forceinline__ float dec8_1(uint u) { return dec8_b((u >> 8) & 0xFFu); }
#endif

#if __has_builtin(__builtin_amdgcn_cvt_pk_fp8_f32)
__device__ __forceinline__ uchar enc8(float f) {
  return (uchar)(__builtin_amdgcn_cvt_pk_fp8_f32(f, f, 0u, false) & 0xFFu);
}
#else
__device__ __forceinline__ uchar enc8(float f) {
  union { float f; uint u; } v; v.f = f;
  uint s = v.u >> 31;
  uint a = v.u & 0x7FFFFFFFu;
  if (a >= 0x43E00000u) return (uchar)((s << 7) | 0x7Eu);  // clamp +-448
  if (a < 0x3C800000u) {                                   // < 2^-6: subnormal
    float q = fabsf(f) * 512.0f;
    uint m = (uint)(q + 0.5f);                             // 0..8 (8 -> 1.0*2^-6)
    return (uchar)((s << 7) | m);
  }
  uint r = a + 0x00080000u;                                // round into bit 20
  if (r >= 0x43E00000u) return (uchar)((s << 7) | 0x7Eu);
  uint ex = (r >> 23) - 120u;
  uint m = (r >> 20) & 7u;
  return (uchar)((s << 7) | (ex << 3) | m);
}
#endif

// ------------------------------- CSR build --------------------------------
__global__ __launch_bounds__(256) void count_kernel(
    const int* __restrict__ dst, int* __restrict__ cnt, int E) {
  int e = blockIdx.x * blockDim.x + threadIdx.x;
  if (e >= E) return;
  atomicAdd(&cnt[dst[e]], 1);
}

__global__ __launch_bounds__(256) void scan_blocks(
    const int* __restrict__ cnt, int* __restrict__ loc,
    int* __restrict__ bsum, int n) {
  __shared__ int ls[4];
  int t = threadIdx.x;
  int base = blockIdx.x * 1024 + t * 4;
  int v[4];
  int s = 0;
#pragma unroll
  for (int i = 0; i < 4; ++i) {
    v[i] = (base + i < n) ? cnt[base + i] : 0;
    s += v[i];
  }
  int lane = t & 63, wid = t >> 6;
  int ps = s;
#pragma unroll
  for (int d = 1; d < 64; d <<= 1) {
    int o = __shfl_up(ps, d, 64);
    if (lane >= d) ps += o;
  }
  if (lane == 63) ls[wid] = ps;
  __syncthreads();
  if (t == 0) {
    int r = 0;
#pragma unroll
    for (int w = 0; w < 4; ++w) { int x = ls[w]; ls[w] = r; r += x; }
  }
  __syncthreads();
  int run = ps - s + ls[wid];
#pragma unroll
  for (int i = 0; i < 4; ++i) {
    if (base + i < n) loc[base + i] = run;
    run += v[i];
  }
  if (t == 255) bsum[blockIdx.x] = ps + ls[wid];
}

__global__ __launch_bounds__(256) void scan_bsums(int* __restrict__ bsum,
                                                  int nb) {
  __shared__ int ls[4];
  int t = threadIdx.x;
  int v = (t < nb) ? bsum[t] : 0;
  int lane = t & 63, wid = t >> 6;
  int ps = v;
#pragma unroll
  for (int d = 1; d < 64; d <<= 1) {
    int o = __shfl_up(ps, d, 64);
    if (lane >= d) ps += o;
  }
  if (lane == 63) ls[wid] = ps;
  __syncthreads();
  if (t == 0) {
    int r = 0;
#pragma unroll
    for (int w = 0; w < 4; ++w) { int x = ls[w]; ls[w] = r; r += x; }
  }
  __syncthreads();
  if (t < nb) bsum[t] = ps - v + ls[wid];
}

__global__ __launch_bounds__(256) void scan_apply(
    const int* __restrict__ loc, const int* __restrict__ bsum,
    int* __restrict__ off, int* __restrict__ cur, int n, int E) {
  int i = blockIdx.x * 256 + threadIdx.x;
  if (i < n) {
    int v = loc[i] + bsum[i >> 10];
    off[i] = v;
    cur[i] = v;
  }
  if (i == 0) off[n] = E;
}

__global__ __launch_bounds__(256) void fill_kernel(
    const int* __restrict__ src, const int* __restrict__ dst,
    int* __restrict__ cur, int* __restrict__ csr, int E) {
  int e = blockIdx.x * blockDim.x + threadIdx.x;
  if (e >= E) return;
  int pos = atomicAdd(&cur[dst[e]], 1);
  csr[pos] = src[e];
}

// --------------------- input prep: noisy + bf16 convert --------------------
// writes XB with INTERLEAVED rows: 2*node = clean, 2*node+1 = noisy.
__global__ __launch_bounds__(256) void noisy_convert(
    const float* __restrict__ x, const float* __restrict__ noise,
    ushort* __restrict__ XB, int N) {
  int node = (blockIdx.x * blockDim.x + threadIdx.x) >> 6;
  int lane = threadIdx.x & 63;
  if (node >= N) return;
  size_t base = (size_t)node * 128 + 2 * lane;
  float2 nz = *(const float2*)(noise + base);
  float ss = nz.x * nz.x + nz.y * nz.y;
#pragma unroll
  for (int m = 1; m < 64; m <<= 1) ss += __shfl_xor(ss, m, 64);
  float scale = 0.1f / fmaxf(sqrtf(ss), 1e-12f);
  float2 xv = *(const float2*)(x + base);
  float s0 = (xv.x > 0.f) ? 1.f : ((xv.x < 0.f) ? -1.f : 0.f);
  float s1 = (xv.y > 0.f) ? 1.f : ((xv.y < 0.f) ? -1.f : 0.f);
  float n0 = xv.x + s0 * nz.x * scale;
  float n1 = xv.y + s1 * nz.y * scale;
  uint pc = ((uint)f2b(xv.y) << 16) | f2b(xv.x);
  uint pn = ((uint)f2b(n1) << 16) | f2b(n0);
  *(uint*)(XB + (size_t)(2 * node) * 128 + 2 * lane) = pc;
  *(uint*)(XB + (size_t)(2 * node + 1) * 128 + 2 * lane) = pn;
}

__global__ __launch_bounds__(256) void conv_weights(
    const float* __restrict__ Wl0, const float* __restrict__ Wr0,
    const float* __restrict__ Wl1, const float* __restrict__ Wr1,
    const float* __restrict__ Wl2, const float* __restrict__ Wr2,
    ushort* __restrict__ WB0, ushort* __restrict__ WB1,
    ushort* __restrict__ WB2) {
  int i = blockIdx.x * 256 + threadIdx.x;
  if (i < 16384) {
    WB0[i] = f2b(Wl0[i]);
    WB0[16384 + i] = f2b(Wr0[i]);
    WB1[i] = f2b(Wl1[i]);
    WB1[16384 + i] = f2b(Wr1[i]);
  }
  if (i < 6016) {
    WB2[i] = f2b(Wl2[i]);
    WB2[6016 + i] = f2b(Wr2[i]);
  }
}

// ------------------------- GEMM layers 0/1 (fused) -------------------------
// A:[M][128] bf16 interleaved rows. W:[256][128] bf16 (Wl 0..127, Wr 128..255).
// One dispatch: 512 threads, 8 waves (wm = row half, wn = 4 col groups x 64).
// cols 0..127 (Wl)  -> Pb: per node {128 bf16 clean}{128 fp8 delta} (384 B)
// cols 128..255 (Wr)-> Rf: [node][2][128] f32
__global__ __launch_bounds__(512) void gemm_fused(
    const ushort* __restrict__ A, const ushort* __restrict__ W,
    ushort* __restrict__ Pb, float* __restrict__ Rf, int M) {
  __shared__ ushort As[128 * 72];   // stride 72 bf16 = 144 B (bank-safe)
  __shared__ ushort Ws[256 * 72];
  int tid = threadIdx.x;
  int lane = tid & 63, wid = tid >> 6;
  int wm = wid & 1, wn = wid >> 1;          // wn in 0..3
  int lrow = lane & 15, quad = lane >> 4;
  int row0 = blockIdx.x * 128;

  f32x4 acc[4][4];
#pragma unroll
  for (int mt = 0; mt < 4; ++mt)
#pragma unroll
    for (int nt = 0; nt < 4; ++nt) acc[mt][nt] = (f32x4)(0.f);

  for (int k0 = 0; k0 < 128; k0 += 64) {
    for (int c = tid; c < 128 * 8; c += 512) {
      int r = c >> 3, kc = c & 7;
      int gr = row0 + r;
      uint4 v = make_uint4(0, 0, 0, 0);
      if (gr < M) v = *(const uint4*)(A + (size_t)gr * 128 + k0 + kc * 8);
      *(uint4*)(As + r * 72 + kc * 8) = v;
    }
    for (int c = tid; c < 256 * 8; c += 512) {
      int r = c >> 3, kc = c & 7;
      uint4 v = *(const uint4*)(W + (size_t)r * 128 + k0 + kc * 8);
      *(uint4*)(Ws + r * 72 + kc * 8) = v;
    }
    __syncthreads();
#pragma unroll
    for (int ks = 0; ks < 64; ks += 32) {
      bf16x8 af[4], bw[4];
#pragma unroll
      for (int mt = 0; mt < 4; ++mt)
        af[mt] = *(const bf16x8*)(As + (wm * 64 + mt * 16 + lrow) * 72 + ks + quad * 8);
#pragma unroll
      for (int nt = 0; nt < 4; ++nt)
        bw[nt] = *(const bf16x8*)(Ws + (wn * 64 + nt * 16 + lrow) * 72 + ks + quad * 8);
#pragma unroll
      for (int mt = 0; mt < 4; ++mt)
#pragma unroll
        for (int nt = 0; nt < 4; ++nt)
          acc[mt][nt] = __builtin_amdgcn_mfma_f32_16x16x32_bf16(
              af[mt], bw[nt], acc[mt][nt], 0, 0, 0);
    }
    __syncthreads();
  }
  // epilogue. C/D layout: col = lane&15, row = quad*4 + rg. Interleaved rows
  // put a node's clean (even rg) and noisy (odd rg) in the SAME lane.
  uchar* Pd = (uchar*)Pb;
  if (wn < 2) {  // Wl -> P (clean bf16 + delta fp8)
#pragma unroll
    for (int mt = 0; mt < 4; ++mt) {
#pragma unroll
      for (int nt = 0; nt < 4; ++nt) {
        int col = wn * 64 + nt * 16 + lrow;
#pragma unroll
        for (int rg = 0; rg < 4; rg += 2) {
          int row = row0 + wm * 64 + mt * 16 + quad * 4 + rg;  // even
          if (row >= M) continue;                              // M even
          int nd = row >> 1;
          float cv = acc[mt][nt][rg];
          float nv = acc[mt][nt][rg + 1];
          ushort cb = f2b(cv);
          float cr = b2f_lo((uint)cb);                 // rounded clean
          Pb[(size_t)nd * 192 + col] = cb;
          Pd[(size_t)nd * 384 + 256 + col] = enc8(nv - cr);
        }
      }
    }
  } else {  // Wr -> R f32 [node][2][128]
#pragma unroll
    for (int mt = 0; mt < 4; ++mt) {
#pragma unroll
      for (int nt = 0; nt < 4; ++nt) {
        int colR = (wn - 2) * 64 + nt * 16 + lrow;
#pragma unroll
        for (int rg = 0; rg < 4; ++rg) {
          int row = row0 + wm * 64 + mt * 16 + quad * 4 + rg;
          if (row >= M) continue;
          int nd = row >> 1, hf = row & 1;
          Rf[(size_t)nd * 256 + hf * 128 + colR] = acc[mt][nt][rg];
        }
      }
    }
  }
}

// ------------------------------ GEMM layer 2 -------------------------------
// 94 W rows (Wl2|Wr2). col<47 -> Pz[node][2][64] bf16; col in [47,94) -> Rz.
__global__ __launch_bounds__(256) void gemm_l2(
    const ushort* __restrict__ A, const ushort* __restrict__ W,
    ushort* __restrict__ Pb, float* __restrict__ Rf, int M) {
  constexpr int NT = 3;
  __shared__ ushort As[128 * 72];
  __shared__ ushort Ws[96 * 72];
  int tid = threadIdx.x;
  int lane = tid & 63, wid = tid >> 6;
  int wm = wid & 1, wn = wid >> 1;
  int lrow = lane & 15, quad = lane >> 4;
  int row0 = blockIdx.x * 128;

  f32x4 acc[4][NT];
#pragma unroll
  for (int mt = 0; mt < 4; ++mt)
#pragma unroll
    for (int nt = 0; nt < NT; ++nt) acc[mt][nt] = (f32x4)(0.f);

  for (int k0 = 0; k0 < 128; k0 += 64) {
    for (int c = tid; c < 128 * 8; c += 256) {
      int r = c >> 3, kc = c & 7;
      int gr = row0 + r;
      uint4 v = make_uint4(0, 0, 0, 0);
      if (gr < M) v = *(const uint4*)(A + (size_t)gr * 128 + k0 + kc * 8);
      *(uint4*)(As + r * 72 + kc * 8) = v;
    }
    for (int c = tid; c < 96 * 8; c += 256) {
      int r = c >> 3, kc = c & 7;
      uint4 v = make_uint4(0, 0, 0, 0);
      if (r < 94) v = *(const uint4*)(W + (size_t)r * 128 + k0 + kc * 8);
      *(uint4*)(Ws + r * 72 + kc * 8) = v;
    }
    __syncthreads();
#pragma unroll
    for (int ks = 0; ks < 64; ks += 32) {
      bf16x8 af[4], bw[NT];
#pragma unroll
      for (int mt = 0; mt < 4; ++mt)
        af[mt] = *(const bf16x8*)(As + (wm * 64 + mt * 16 + lrow) * 72 + ks + quad * 8);
#pragma unroll
      for (int nt = 0; nt < NT; ++nt)
        bw[nt] = *(const bf16x8*)(Ws + (wn * NT * 16 + nt * 16 + lrow) * 72 + ks + quad * 8);
#pragma unroll
      for (int mt = 0; mt < 4; ++mt)
#pragma unroll
        for (int nt = 0; nt < NT; ++nt)
          acc[mt][nt] = __builtin_amdgcn_mfma_f32_16x16x32_bf16(
              af[mt], bw[nt], acc[mt][nt], 0, 0, 0);
    }
    __syncthreads();
  }
#pragma unroll
  for (int mt = 0; mt < 4; ++mt) {
#pragma unroll
    for (int nt = 0; nt < NT; ++nt) {
#pragma unroll
      for (int rg = 0; rg < 4; ++rg) {
        int row = row0 + wm * 64 + mt * 16 + quad * 4 + rg;
        if (row >= M) continue;
        int col = wn * NT * 16 + nt * 16 + lrow;
        int nd = row >> 1, hf = row & 1;
        float v = acc[mt][nt][rg];
        if (col < 47)
          Pb[(size_t)nd * 128 + hf * 64 + col] = f2b(v);
        else if (col < 94)
          Rf[(size_t)nd * 128 + hf * 64 + (col - 47)] = v;
      }
    }
  }
}

// ------------------------------ aggregation --------------------------------
// Layers 0/1: 1 wave per NODE. Per edge: 256 B clean (uint/lane, 2 cols) +
// 128 B fp8 delta (ushort/lane). noisy_sum = clean_sum + delta_sum.
template <bool WF32>
__global__ __launch_bounds__(256) void agg_dual128(
    const ushort* __restrict__ P2, const float* __restrict__ R2,
    const float* __restrict__ bias, const int* __restrict__ off,
    const int* __restrict__ csr, float* __restrict__ f0,
    float* __restrict__ f1, ushort* __restrict__ bout, int N) {
  int node = (blockIdx.x * blockDim.x + threadIdx.x) >> 6;
  int lane = threadIdx.x & 63;
  if (node >= N) return;
  const uchar* PB = (const uchar*)P2;
  int b = off[node], e = off[node + 1];
  float ac0 = 0.f, ac1 = 0.f, bc0 = 0.f, bc1 = 0.f;   // clean partials
  float ad0 = 0.f, ad1 = 0.f, bd0 = 0.f, bd1 = 0.f;   // delta partials
  int j = b;
  for (; j + 8 <= e; j += 8) {
    int s0 = csr[j],     s1 = csr[j + 1], s2 = csr[j + 2], s3 = csr[j + 3];
    int s4 = csr[j + 4], s5 = csr[j + 5], s6 = csr[j + 6], s7 = csr[j + 7];
    const uchar* p0 = PB + (size_t)s0 * 384;
    const uchar* p1 = PB + (size_t)s1 * 384;
    const uchar* p2 = PB + (size_t)s2 * 384;
    const uchar* p3 = PB + (size_t)s3 * 384;
    const uchar* p4 = PB + (size_t)s4 * 384;
    const uchar* p5 = PB + (size_t)s5 * 384;
    const uchar* p6 = PB + (size_t)s6 * 384;
    const uchar* p7 = PB + (size_t)s7 * 384;
    uint c0 = *(const uint*)(p0 + 4 * lane);
    uint c1 = *(const uint*)(p1 + 4 * lane);
    uint c2 = *(const uint*)(p2 + 4 * lane);
    uint c3 = *(const uint*)(p3 + 4 * lane);
    uint c4 = *(const uint*)(p4 + 4 * lane);
    uint c5 = *(const uint*)(p5 + 4 * lane);
    uint c6 = *(const uint*)(p6 + 4 * lane);
    uint c7 = *(const uint*)(p7 + 4 * lane);
    uint d0 = *(const ushort*)(p0 + 256 + 2 * lane);
    uint d1 = *(const ushort*)(p1 + 256 + 2 * lane);
    uint d2 = *(const ushort*)(p2 + 256 + 2 * lane);
    uint d3 = *(const ushort*)(p3 + 256 + 2 * lane);
    uint d4 = *(const ushort*)(p4 + 256 + 2 * lane);
    uint d5 = *(const ushort*)(p5 + 256 + 2 * lane);
    uint d6 = *(const ushort*)(p6 + 256 + 2 * lane);
    uint d7 = *(const ushort*)(p7 + 256 + 2 * lane);
    ac0 += b2f_lo(c0) + b2f_lo(c1) + b2f_lo(c2) + b2f_lo(c3);
    ac1 += b2f_hi(c0) + b2f_hi(c1) + b2f_hi(c2) + b2f_hi(c3);
    bc0 += b2f_lo(c4) + b2f_lo(c5) + b2f_lo(c6) + b2f_lo(c7);
    bc1 += b2f_hi(c4) + b2f_hi(c5) + b2f_hi(c6) + b2f_hi(c7);
    ad0 += dec8_0(d0) + dec8_0(d1) + dec8_0(d2) + dec8_0(d3);
    ad1 += dec8_1(d0) + dec8_1(d1) + dec8_1(d2) + dec8_1(d3);
    bd0 += dec8_0(d4) + dec8_0(d5) + dec8_0(d6) + dec8_0(d7);
    bd1 += dec8_1(d4) + dec8_1(d5) + dec8_1(d6) + dec8_1(d7);
  }
  if (j + 4 <= e) {
    int s0 = csr[j], s1 = csr[j + 1], s2 = csr[j + 2], s3 = csr[j + 3];
    const uchar* p0 = PB + (size_t)s0 * 384;
    const uchar* p1 = PB + (size_t)s1 * 384;
    const uchar* p2 = PB + (size_t)s2 * 384;
    const uchar* p3 = PB + (size_t)s3 * 384;
    uint c0 = *(const uint*)(p0 + 4 * lane);
    uint c1 = *(const uint*)(p1 + 4 * lane);
    uint c2 = *(const uint*)(p2 + 4 * lane);
    uint c3 = *(const uint*)(p3 + 4 * lane);
    uint d0 = *(const ushort*)(p0 + 256 + 2 * lane);
    uint d1 = *(const ushort*)(p1 + 256 + 2 * lane);
    uint d2 = *(const ushort*)(p2 + 256 + 2 * lane);
    uint d3 = *(const ushort*)(p3 + 256 + 2 * lane);
    ac0 += b2f_lo(c0) + b2f_lo(c1) + b2f_lo(c2) + b2f_lo(c3);
    ac1 += b2f_hi(c0) + b2f_hi(c1) + b2f_hi(c2) + b2f_hi(c3);
    ad0 += dec8_0(d0) + dec8_0(d1) + dec8_0(d2) + dec8_0(d3);
    ad1 += dec8_1(d0) + dec8_1(d1) + dec8_1(d2) + dec8_1(d3);
    j += 4;
  }
  for (; j < e; ++j) {
    const uchar* p0 = PB + (size_t)csr[j] * 384;
    uint c0 = *(const uint*)(p0 + 4 * lane);
    uint d0 = *(const ushort*)(p0 + 256 + 2 * lane);
    ac0 += b2f_lo(c0);
    ac1 += b2f_hi(c0);
    ad0 += dec8_0(d0);
    ad1 += dec8_1(d0);
  }
  ac0 += bc0; ac1 += bc1; ad0 += bd0; ad1 += bd1;
  float an0 = ac0 + ad0, an1 = ac1 + ad1;  // noisy = clean + delta
  float invd = 1.f / (float)max(e - b, 1);
  float2 rc = *(const float2*)(R2 + (size_t)node * 256 + 2 * lane);
  float2 rn = *(const float2*)(R2 + (size_t)node * 256 + 128 + 2 * lane);
  float2 bb = *(const float2*)(bias + 2 * lane);
  float oc0 = fmaxf(ac0 * invd + bb.x + rc.x, 0.f);
  float oc1 = fmaxf(ac1 * invd + bb.y + rc.y, 0.f);
  float on0 = fmaxf(an0 * invd + bb.x + rn.x, 0.f);
  float on1 = fmaxf(an1 * invd + bb.y + rn.y, 0.f);
  uint pc = ((uint)f2b(oc1) << 16) | f2b(oc0);
  uint pn = ((uint)f2b(on1) << 16) | f2b(on0);
  *(uint*)(bout + (size_t)(2 * node) * 128 + 2 * lane) = pc;
  *(uint*)(bout + (size_t)(2 * node + 1) * 128 + 2 * lane) = pn;
  if (WF32) {
    *(float2*)(f0 + (size_t)node * 128 + 2 * lane) = make_float2(oc0, oc1);
    *(float2*)(f1 + (size_t)node * 128 + 2 * lane) = make_float2(on0, on1);
  }
}

// layer 2: Pz/Rz [node][2][64]; 1 wave per node, 2 cols/lane; fused softmax.
__global__ __launch_bounds__(256) void agg47_dual(
    const ushort* __restrict__ Pz, const float* __restrict__ Rz,
    const float* __restrict__ bias, const int* __restrict__ off,
    const int* __restrict__ csr, float* __restrict__ z0,
    float* __restrict__ z1, float* __restrict__ y0, float* __restrict__ y1,
    int N) {
  int node = (blockIdx.x * blockDim.x + threadIdx.x) >> 6;
  int lane = threadIdx.x & 63;
  if (node >= N) return;
  int half = lane >> 5, lq = lane & 31;
  int c0 = 2 * lq, c1 = 2 * lq + 1;
  bool v0 = c0 < 47, v1 = c1 < 47;
  int b = off[node], e = off[node + 1];
  float a0 = 0.f, a1 = 0.f, d0 = 0.f, d1 = 0.f;
  int j = b;
  for (; j + 8 <= e; j += 8) {
    int s0 = csr[j], s1 = csr[j + 1], s2 = csr[j + 2], s3 = csr[j + 3];
    int s4 = csr[j + 4], s5 = csr[j + 5], s6 = csr[j + 6], s7 = csr[j + 7];
    uint u0 = *(const uint*)(Pz + (size_t)s0 * 128 + 2 * lane);
    uint u1 = *(const uint*)(Pz + (size_t)s1 * 128 + 2 * lane);
    uint u2 = *(const uint*)(Pz + (size_t)s2 * 128 + 2 * lane);
    uint u3 = *(const uint*)(Pz + (size_t)s3 * 128 + 2 * lane);
    uint u4 = *(const uint*)(Pz + (size_t)s4 * 128 + 2 * lane);
    uint u5 = *(const uint*)(Pz + (size_t)s5 * 128 + 2 * lane);
    uint u6 = *(const uint*)(Pz + (size_t)s6 * 128 + 2 * lane);
    uint u7 = *(const uint*)(Pz + (size_t)s7 * 128 + 2 * lane);
    a0 += b2f_lo(u0) + b2f_lo(u1) + b2f_lo(u2) + b2f_lo(u3);
    a1 += b2f_hi(u0) + b2f_hi(u1) + b2f_hi(u2) + b2f_hi(u3);
    d0 += b2f_lo(u4) + b2f_lo(u5) + b2f_lo(u6) + b2f_lo(u7);
    d1 += b2f_hi(u4) + b2f_hi(u5) + b2f_hi(u6) + b2f_hi(u7);
  }
  if (j + 4 <= e) {
    int s0 = csr[j], s1 = csr[j + 1], s2 = csr[j + 2], s3 = csr[j + 3];
    uint u0 = *(const uint*)(Pz + (size_t)s0 * 128 + 2 * lane);
    uint u1 = *(const uint*)(Pz + (size_t)s1 * 128 + 2 * lane);
    uint u2 = *(const uint*)(Pz + (size_t)s2 * 128 + 2 * lane);
    uint u3 = *(const uint*)(Pz + (size_t)s3 * 128 + 2 * lane);
    a0 += b2f_lo(u0) + b2f_lo(u1) + b2f_lo(u2) + b2f_lo(u3);
    a1 += b2f_hi(u0) + b2f_hi(u1) + b2f_hi(u2) + b2f_hi(u3);
    j += 4;
  }
  for (; j < e; ++j) {
    uint u0 = *(const uint*)(Pz + (size_t)csr[j] * 128 + 2 * lane);
    a0 += b2f_lo(u0);
    a1 += b2f_hi(u0);
  }
  a0 += d0; a1 += d1;
  float invd = 1.f / (float)max(e - b, 1);
  float2 rv = *(const float2*)(Rz + (size_t)node * 128 + 2 * lane);
  float za = v0 ? (a0 * invd + bias[c0] + rv.x) : -INFINITY;
  float zb = v1 ? (a1 * invd + bias[c1] + rv.y) : -INFINITY;
  float m = fmaxf(za, zb);
#pragma unroll
  for (int d = 1; d < 32; d <<= 1) m = fmaxf(m, __shfl_xor(m, d, 64));
  float s = (v0 ? __expf(za - m) : 0.f) + (v1 ? __expf(zb - m) : 0.f);
#pragma unroll
  for (int d = 1; d < 32; d <<= 1) s += __shfl_xor(s, d, 64);
  float ls = logf(s) + m;
  float* zo = (half ? z1 : z0) + (size_t)node * 47;
  float* yo = (half ? y1 : y0) + (size_t)node * 47;
  if (v0) { zo[c0] = za; yo[c0] = za - ls; }
  if (v1) { zo[c1] = zb; yo[c1] = zb - ls; }
}

// ---------------------------------------------------------------------------
extern "C" void kernel_launch(void* const* d_in, const int* in_sizes, int n_in,
                              void* d_out, int out_size, void* d_ws,
                              size_t ws_size, hipStream_t stream) {
  const float* x = (const float*)d_in[0];
  const int* ei = (const int*)d_in[1];
  const float* noise = (const float*)d_in[2];
  const float* Wl0 = (const float*)d_in[3];
  const float* bl0 = (const float*)d_in[4];
  const float* Wr0 = (const float*)d_in[5];
  const float* Wl1 = (const float*)d_in[6];
  const float* bl1 = (const float*)d_in[7];
  const float* Wr1 = (const float*)d_in[8];
  const float* Wl2 = (const float*)d_in[9];
  const float* bl2 = (const float*)d_in[10];
  const float* Wr2 = (const float*)d_in[11];

  const int N = in_sizes[0] / 128;
  const int E = in_sizes[1] / 2;
  const int M = 2 * N;

  float* out = (float*)d_out;
  float* h_p = out;
  float* y_p = h_p + (size_t)N * 128;
  float* z_p = y_p + (size_t)N * 47;
  float* h_n = z_p + (size_t)N * 47;
  float* y_n = h_n + (size_t)N * 128;
  float* z_n = y_n + (size_t)N * 47;

  char* w = (char*)d_ws;
  auto alloc = [&](size_t bytes) {
    void* p = (void*)w;
    w += (bytes + 511) & ~(size_t)511;
    return p;
  };
  ushort* XB = (ushort*)alloc((size_t)M * 128 * 2);   // bf16 [M][128] interleaved
  ushort* Pb = (ushort*)alloc((size_t)N * 384);       // P (384B rows) / Pz (256B)
  float* Rf = (float*)alloc((size_t)M * 128 * 4);     // R / Rz
  ushort* WB0 = (ushort*)alloc(256 * 128 * 2);
  ushort* WB1 = (ushort*)alloc(256 * 128 * 2);
  ushort* WB2 = (ushort*)alloc(94 * 128 * 2);
  int* cnt = (int*)alloc((size_t)N * 4);
  int* off = (int*)alloc((size_t)(N + 1) * 4);
  int* cur = (int*)alloc((size_t)N * 4);
  int* loc = (int*)alloc((size_t)N * 4);
  int* bsum = (int*)alloc((size_t)256 * 4);
  int* csr = (int*)alloc((size_t)E * 4);

  conv_weights<<<(16384 + 255) / 256, 256, 0, stream>>>(
      Wl0, Wr0, Wl1, Wr1, Wl2, Wr2, WB0, WB1, WB2);

  // CSR build
  hipMemsetAsync(cnt, 0, (size_t)N * 4, stream);
  int eb = (E + 255) / 256;
  count_kernel<<<eb, 256, 0, stream>>>(ei + E, cnt, E);
  int sb = (N + 1023) / 1024;
  scan_blocks<<<sb, 256, 0, stream>>>(cnt, loc, bsum, N);
  scan_bsums<<<1, 256, 0, stream>>>(bsum, sb);
  scan_apply<<<(N + 255) / 256, 256, 0, stream>>>(loc, bsum, off, cur, N, E);
  fill_kernel<<<eb, 256, 0, stream>>>(ei, ei + E, cur, csr, E);

  int nwb = (N + 3) / 4;       // 1 wave/node
  int rb = (M + 127) / 128;    // GEMM row blocks

  noisy_convert<<<nwb, 256, 0, stream>>>(x, noise, XB, N);

  // layer 0
  gemm_fused<<<rb, 512, 0, stream>>>(XB, WB0, Pb, Rf, M);
  agg_dual128<false><<<nwb, 256, 0, stream>>>(Pb, Rf, bl0, off, csr, nullptr,
                                              nullptr, XB, N);
  // layer 1 (h outputs + bf16 for next layer)
  gemm_fused<<<rb, 512, 0, stream>>>(XB, WB1, Pb, Rf, M);
  agg_dual128<true><<<nwb, 256, 0, stream>>>(Pb, Rf, bl1, off, csr, h_p, h_n,
                                             XB, N);
  // layer 2 + fused log_softmax
  gemm_l2<<<rb, 256, 0, stream>>>(XB, WB2, Pb, Rf, M);
  agg47_dual<<<nwb, 256, 0, stream>>>(Pb, Rf, bl2, off, csr, z_p, z_n, y_p,
                                      y_n, N);
}

// Round 2
// 415.895 us; speedup vs baseline: 1.1906x; 1.1150x over previous
//
#include <hip/hip_runtime.h>
#include <math.h>

// ---------------------------------------------------------------------------
// SAGE pipeline, bf16-MFMA, round-7: full-fp8 gather rows (256 B, 2 lines).
//   Layers 0/1 gather table P8: per node {128 fp8 clean | 128 fp8 delta},
//   delta re-based on ROUNDED clean so noisy = dec(clean8)+dec(delta8) has
//   only fp8-on-delta error (~3e-3). Clean branch carries fp8 err ~5e-3
//   after the degree-16 mean (predicted absmax ~0.045, was 0.03125).
//   One uint/lane covers the whole row: lanes 0-31 accumulate clean cols,
//   lanes 32-63 delta cols; recombine with one __shfl_xor(.,32).
//   Layer 2: clean stays bf16 [node][64] (logits |z|~8: fp8 spacing 0.25-1.0
//   too coarse) + separate fp8 delta table [node][64] (3.2 MB, ~L2-resident).
//   CSR: count stores each edge's rank -> fill is atomic-free.
//   Round-6 post-mortem: FETCH 205->157 MB tracked the 512->384B row cut
//   exactly; gather is compulsory-miss bound (8 XCD x full table) at
//   ~4.05 TB/s on the L2-fill path -> row BYTES are the only lever.
// ---------------------------------------------------------------------------

typedef unsigned int uint;
typedef unsigned short ushort;
typedef unsigned char uchar;
typedef short bf16x8 __attribute__((ext_vector_type(8)));
typedef float f32x4 __attribute__((ext_vector_type(4)));

__device__ __forceinline__ ushort f2b(float f) {  // fp32 -> bf16 RNE
  union { float f; uint u; } v; v.f = f;
  uint u = v.u;
  return (ushort)((u + 0x7FFFu + ((u >> 16) & 1u)) >> 16);
}
__device__ __forceinline__ float b2f_lo(uint u) {
  union { uint u; float f; } v; v.u = u << 16; return v.f;
}
__device__ __forceinline__ float b2f_hi(uint u) {
  union { uint u; float f; } v; v.u = u & 0xFFFF0000u; return v.f;
}

// ---- fp8 e4m3 helpers (hardware cvt on gfx950; guarded sw fallback) -------
#if __has_builtin(__builtin_amdgcn_cvt_f32_fp8)
__device__ __forceinline__ float dec8_0(uint u) { return __builtin_amdgcn_cvt_f32_fp8(u, 0); }
__device__ __forceinline__ float dec8_1(uint u) { return __builtin_amdgcn_cvt_f32_fp8(u, 1); }
__device__ __forceinline__ float dec8_2(uint u) { return __builtin_amdgcn_cvt_f32_fp8(u, 2); }
__device__ __forceinline__ float dec8_3(uint u) { return __builtin_amdgcn_cvt_f32_fp8(u, 3); }
#else
__device__ __forceinline__ float dec8_b(uint b) {
  uint s = (b >> 7) & 1u, ex = (b >> 3) & 0xFu, m = b & 7u;
  union { uint u; float f; } v;
  if (ex == 0) {
    v.f = (float)m * 0.001953125f;  // m * 2^-9
    v.u |= s << 31;
    return v.f;
  }
  v.u = (s << 31) | ((ex + 120u) << 23) | (m << 20);
  return v.f;
}
__device__ __forceinline__ float dec8_0(uint u) { return dec8_b(u & 0xFFu); }
__device__ __forceinline__ float dec8_1(uint u) { return dec8_b((u >> 8) & 0xFFu); }
__device__ __forceinline__ float dec8_2(uint u) { return dec8_b((u >> 16) & 0xFFu); }
__device__ __forceinline__ float dec8_3(uint u) { return dec8_b((u >> 24) & 0xFFu); }
#endif

#if __has_builtin(__builtin_amdgcn_cvt_pk_fp8_f32)
__device__ __forceinline__ uchar enc8(float f) {
  return (uchar)(__builtin_amdgcn_cvt_pk_fp8_f32(f, f, 0u, false) & 0xFFu);
}
#else
__device__ __forceinline__ uchar enc8(float f) {
  union { float f; uint u; } v; v.f = f;
  uint s = v.u >> 31;
  uint a = v.u & 0x7FFFFFFFu;
  if (a >= 0x43E00000u) return (uchar)((s << 7) | 0x7Eu);  // clamp +-448
  if (a < 0x3C800000u) {                                   // < 2^-6: subnormal
    float q = fabsf(f) * 512.0f;
    uint m = (uint)(q + 0.5f);
    return (uchar)((s << 7) | m);
  }
  uint r = a + 0x00080000u;
  if (r >= 0x43E00000u) return (uchar)((s << 7) | 0x7Eu);
  uint ex = (r >> 23) - 120u;
  uint m = (r >> 20) & 7u;
  return (uchar)((s << 7) | (ex << 3) | m);
}
#endif

// ------------------------------- CSR build --------------------------------
// count also emits each edge's rank within its dst bucket -> fill needs no
// atomics (saves a full E-wide atomic pass).
__global__ __launch_bounds__(256) void count_kernel(
    const int* __restrict__ dst, int* __restrict__ cnt,
    int* __restrict__ rank, int E) {
  int e = blockIdx.x * blockDim.x + threadIdx.x;
  if (e >= E) return;
  rank[e] = atomicAdd(&cnt[dst[e]], 1);
}

__global__ __launch_bounds__(256) void scan_blocks(
    const int* __restrict__ cnt, int* __restrict__ loc,
    int* __restrict__ bsum, int n) {
  __shared__ int ls[4];
  int t = threadIdx.x;
  int base = blockIdx.x * 1024 + t * 4;
  int v[4];
  int s = 0;
#pragma unroll
  for (int i = 0; i < 4; ++i) {
    v[i] = (base + i < n) ? cnt[base + i] : 0;
    s += v[i];
  }
  int lane = t & 63, wid = t >> 6;
  int ps = s;
#pragma unroll
  for (int d = 1; d < 64; d <<= 1) {
    int o = __shfl_up(ps, d, 64);
    if (lane >= d) ps += o;
  }
  if (lane == 63) ls[wid] = ps;
  __syncthreads();
  if (t == 0) {
    int r = 0;
#pragma unroll
    for (int w = 0; w < 4; ++w) { int x = ls[w]; ls[w] = r; r += x; }
  }
  __syncthreads();
  int run = ps - s + ls[wid];
#pragma unroll
  for (int i = 0; i < 4; ++i) {
    if (base + i < n) loc[base + i] = run;
    run += v[i];
  }
  if (t == 255) bsum[blockIdx.x] = ps + ls[wid];
}

__global__ __launch_bounds__(256) void scan_bsums(int* __restrict__ bsum,
                                                  int nb) {
  __shared__ int ls[4];
  int t = threadIdx.x;
  int v = (t < nb) ? bsum[t] : 0;
  int lane = t & 63, wid = t >> 6;
  int ps = v;
#pragma unroll
  for (int d = 1; d < 64; d <<= 1) {
    int o = __shfl_up(ps, d, 64);
    if (lane >= d) ps += o;
  }
  if (lane == 63) ls[wid] = ps;
  __syncthreads();
  if (t == 0) {
    int r = 0;
#pragma unroll
    for (int w = 0; w < 4; ++w) { int x = ls[w]; ls[w] = r; r += x; }
  }
  __syncthreads();
  if (t < nb) bsum[t] = ps - v + ls[wid];
}

__global__ __launch_bounds__(256) void scan_apply(
    const int* __restrict__ loc, const int* __restrict__ bsum,
    int* __restrict__ off, int n, int E) {
  int i = blockIdx.x * 256 + threadIdx.x;
  if (i < n) off[i] = loc[i] + bsum[i >> 10];
  if (i == 0) off[n] = E;
}

__global__ __launch_bounds__(256) void fill_kernel(
    const int* __restrict__ src, const int* __restrict__ dst,
    const int* __restrict__ rank, const int* __restrict__ off,
    int* __restrict__ csr, int E) {
  int e = blockIdx.x * blockDim.x + threadIdx.x;
  if (e >= E) return;
  csr[off[dst[e]] + rank[e]] = src[e];
}

// --------------------- input prep: noisy + bf16 convert --------------------
// writes XB with INTERLEAVED rows: 2*node = clean, 2*node+1 = noisy.
__global__ __launch_bounds__(256) void noisy_convert(
    const float* __restrict__ x, const float* __restrict__ noise,
    ushort* __restrict__ XB, int N) {
  int node = (blockIdx.x * blockDim.x + threadIdx.x) >> 6;
  int lane = threadIdx.x & 63;
  if (node >= N) return;
  size_t base = (size_t)node * 128 + 2 * lane;
  float2 nz = *(const float2*)(noise + base);
  float ss = nz.x * nz.x + nz.y * nz.y;
#pragma unroll
  for (int m = 1; m < 64; m <<= 1) ss += __shfl_xor(ss, m, 64);
  float scale = 0.1f / fmaxf(sqrtf(ss), 1e-12f);
  float2 xv = *(const float2*)(x + base);
  float s0 = (xv.x > 0.f) ? 1.f : ((xv.x < 0.f) ? -1.f : 0.f);
  float s1 = (xv.y > 0.f) ? 1.f : ((xv.y < 0.f) ? -1.f : 0.f);
  float n0 = xv.x + s0 * nz.x * scale;
  float n1 = xv.y + s1 * nz.y * scale;
  uint pc = ((uint)f2b(xv.y) << 16) | f2b(xv.x);
  uint pn = ((uint)f2b(n1) << 16) | f2b(n0);
  *(uint*)(XB + (size_t)(2 * node) * 128 + 2 * lane) = pc;
  *(uint*)(XB + (size_t)(2 * node + 1) * 128 + 2 * lane) = pn;
}

__global__ __launch_bounds__(256) void conv_weights(
    const float* __restrict__ Wl0, const float* __restrict__ Wr0,
    const float* __restrict__ Wl1, const float* __restrict__ Wr1,
    const float* __restrict__ Wl2, const float* __restrict__ Wr2,
    ushort* __restrict__ WB0, ushort* __restrict__ WB1,
    ushort* __restrict__ WB2) {
  int i = blockIdx.x * 256 + threadIdx.x;
  if (i < 16384) {
    WB0[i] = f2b(Wl0[i]);
    WB0[16384 + i] = f2b(Wr0[i]);
    WB1[i] = f2b(Wl1[i]);
    WB1[16384 + i] = f2b(Wr1[i]);
  }
  if (i < 6016) {
    WB2[i] = f2b(Wl2[i]);
    WB2[6016 + i] = f2b(Wr2[i]);
  }
}

// ------------------------- GEMM layers 0/1 (fused) -------------------------
// A:[M][128] bf16 interleaved rows. W:[256][128] bf16 (Wl 0..127, Wr 128..255).
// 512 threads, 8 waves. cols 0..127 (Wl) -> P8: per node
// {128 fp8 clean | 128 fp8 delta} (256 B rows). cols 128..255 (Wr) -> Rf f32.
__global__ __launch_bounds__(512) void gemm_fused(
    const ushort* __restrict__ A, const ushort* __restrict__ W,
    uchar* __restrict__ P8, float* __restrict__ Rf, int M) {
  __shared__ ushort As[128 * 72];   // stride 72 bf16 = 144 B (bank-safe)
  __shared__ ushort Ws[256 * 72];
  int tid = threadIdx.x;
  int lane = tid & 63, wid = tid >> 6;
  int wm = wid & 1, wn = wid >> 1;          // wn in 0..3
  int lrow = lane & 15, quad = lane >> 4;
  int row0 = blockIdx.x * 128;

  f32x4 acc[4][4];
#pragma unroll
  for (int mt = 0; mt < 4; ++mt)
#pragma unroll
    for (int nt = 0; nt < 4; ++nt) acc[mt][nt] = (f32x4)(0.f);

  for (int k0 = 0; k0 < 128; k0 += 64) {
    for (int c = tid; c < 128 * 8; c += 512) {
      int r = c >> 3, kc = c & 7;
      int gr = row0 + r;
      uint4 v = make_uint4(0, 0, 0, 0);
      if (gr < M) v = *(const uint4*)(A + (size_t)gr * 128 + k0 + kc * 8);
      *(uint4*)(As + r * 72 + kc * 8) = v;
    }
    for (int c = tid; c < 256 * 8; c += 512) {
      int r = c >> 3, kc = c & 7;
      uint4 v = *(const uint4*)(W + (size_t)r * 128 + k0 + kc * 8);
      *(uint4*)(Ws + r * 72 + kc * 8) = v;
    }
    __syncthreads();
#pragma unroll
    for (int ks = 0; ks < 64; ks += 32) {
      bf16x8 af[4], bw[4];
#pragma unroll
      for (int mt = 0; mt < 4; ++mt)
        af[mt] = *(const bf16x8*)(As + (wm * 64 + mt * 16 + lrow) * 72 + ks + quad * 8);
#pragma unroll
      for (int nt = 0; nt < 4; ++nt)
        bw[nt] = *(const bf16x8*)(Ws + (wn * 64 + nt * 16 + lrow) * 72 + ks + quad * 8);
#pragma unroll
      for (int mt = 0; mt < 4; ++mt)
#pragma unroll
        for (int nt = 0; nt < 4; ++nt)
          acc[mt][nt] = __builtin_amdgcn_mfma_f32_16x16x32_bf16(
              af[mt], bw[nt], acc[mt][nt], 0, 0, 0);
    }
    __syncthreads();
  }
  // epilogue. C/D layout: col = lane&15, row = quad*4 + rg. Interleaved rows
  // put a node's clean (even rg) and noisy (odd rg) in the SAME lane.
  if (wn < 2) {  // Wl -> P8 (fp8 clean + fp8 delta vs ROUNDED clean)
#pragma unroll
    for (int mt = 0; mt < 4; ++mt) {
#pragma unroll
      for (int nt = 0; nt < 4; ++nt) {
        int col = wn * 64 + nt * 16 + lrow;
#pragma unroll
        for (int rg = 0; rg < 4; rg += 2) {
          int row = row0 + wm * 64 + mt * 16 + quad * 4 + rg;  // even
          if (row >= M) continue;                              // M even
          int nd = row >> 1;
          float cv = acc[mt][nt][rg];
          float nv = acc[mt][nt][rg + 1];
          uchar c8 = enc8(cv);
          float cr = dec8_0((uint)c8);                 // rounded clean
          P8[(size_t)nd * 256 + col] = c8;
          P8[(size_t)nd * 256 + 128 + col] = enc8(nv - cr);
        }
      }
    }
  } else {  // Wr -> R f32 [node][2][128]
#pragma unroll
    for (int mt = 0; mt < 4; ++mt) {
#pragma unroll
      for (int nt = 0; nt < 4; ++nt) {
        int colR = (wn - 2) * 64 + nt * 16 + lrow;
#pragma unroll
        for (int rg = 0; rg < 4; ++rg) {
          int row = row0 + wm * 64 + mt * 16 + quad * 4 + rg;
          if (row >= M) continue;
          int nd = row >> 1, hf = row & 1;
          Rf[(size_t)nd * 256 + hf * 128 + colR] = acc[mt][nt][rg];
        }
      }
    }
  }
}

// ------------------------------ GEMM layer 2 -------------------------------
// 94 W rows (Wl2|Wr2). col<47 -> Pzc bf16 [node][64] + Pzd fp8 [node][64];
// col in [47,94) -> Rz f32 [node][2][64] (clean 0..63, noisy 64..127).
__global__ __launch_bounds__(256) void gemm_l2(
    const ushort* __restrict__ A, const ushort* __restrict__ W,
    ushort* __restrict__ Pzc, uchar* __restrict__ Pzd,
    float* __restrict__ Rz, int M) {
  constexpr int NT = 3;
  __shared__ ushort As[128 * 72];
  __shared__ ushort Ws[96 * 72];
  int tid = threadIdx.x;
  int lane = tid & 63, wid = tid >> 6;
  int wm = wid & 1, wn = wid >> 1;
  int lrow = lane & 15, quad = lane >> 4;
  int row0 = blockIdx.x * 128;

  f32x4 acc[4][NT];
#pragma unroll
  for (int mt = 0; mt < 4; ++mt)
#pragma unroll
    for (int nt = 0; nt < NT; ++nt) acc[mt][nt] = (f32x4)(0.f);

  for (int k0 = 0; k0 < 128; k0 += 64) {
    for (int c = tid; c < 128 * 8; c += 256) {
      int r = c >> 3, kc = c & 7;
      int gr = row0 + r;
      uint4 v = make_uint4(0, 0, 0, 0);
      if (gr < M) v = *(const uint4*)(A + (size_t)gr * 128 + k0 + kc * 8);
      *(uint4*)(As + r * 72 + kc * 8) = v;
    }
    for (int c = tid; c < 96 * 8; c += 256) {
      int r = c >> 3, kc = c & 7;
      uint4 v = make_uint4(0, 0, 0, 0);
      if (r < 94) v = *(const uint4*)(W + (size_t)r * 128 + k0 + kc * 8);
      *(uint4*)(Ws + r * 72 + kc * 8) = v;
    }
    __syncthreads();
#pragma unroll
    for (int ks = 0; ks < 64; ks += 32) {
      bf16x8 af[4], bw[NT];
#pragma unroll
      for (int mt = 0; mt < 4; ++mt)
        af[mt] = *(const bf16x8*)(As + (wm * 64 + mt * 16 + lrow) * 72 + ks + quad * 8);
#pragma unroll
      for (int nt = 0; nt < NT; ++nt)
        bw[nt] = *(const bf16x8*)(Ws + (wn * NT * 16 + nt * 16 + lrow) * 72 + ks + quad * 8);
#pragma unroll
      for (int mt = 0; mt < 4; ++mt)
#pragma unroll
        for (int nt = 0; nt < NT; ++nt)
          acc[mt][nt] = __builtin_amdgcn_mfma_f32_16x16x32_bf16(
              af[mt], bw[nt], acc[mt][nt], 0, 0, 0);
    }
    __syncthreads();
  }
#pragma unroll
  for (int mt = 0; mt < 4; ++mt) {
#pragma unroll
    for (int nt = 0; nt < NT; ++nt) {
      int col = wn * NT * 16 + nt * 16 + lrow;
#pragma unroll
      for (int rg = 0; rg < 4; rg += 2) {
        int row = row0 + wm * 64 + mt * 16 + quad * 4 + rg;  // even (clean)
        if (row >= M) continue;
        int nd = row >> 1;
        float cv = acc[mt][nt][rg];
        float nv = acc[mt][nt][rg + 1];
        if (col < 47) {
          ushort cb = f2b(cv);
          Pzc[(size_t)nd * 64 + col] = cb;
          Pzd[(size_t)nd * 64 + col] = enc8(nv - b2f_lo((uint)cb));
        } else if (col < 94) {
          Rz[(size_t)nd * 128 + (col - 47)] = cv;
          Rz[(size_t)nd * 128 + 64 + (col - 47)] = nv;
        }
      }
    }
  }
}

// ------------------------------ aggregation --------------------------------
// Layers 0/1: 1 wave per NODE. ONE uint per lane covers the full 256 B row:
// lanes 0-31 accumulate clean cols 4lq..4lq+3, lanes 32-63 the delta cols.
// Recombine with __shfl_xor(.,32): noisy_sum = clean_sum + delta_sum.
template <bool WF32>
__global__ __launch_bounds__(256) void agg_dual128(
    const uchar* __restrict__ P8, const float* __restrict__ R2,
    const float* __restrict__ bias, const int* __restrict__ off,
    const int* __restrict__ csr, float* __restrict__ f0,
    float* __restrict__ f1, ushort* __restrict__ bout, int N) {
  int node = (blockIdx.x * blockDim.x + threadIdx.x) >> 6;
  int lane = threadIdx.x & 63;
  if (node >= N) return;
  int lq = lane & 31;
  int b = off[node], e = off[node + 1];
  float s0 = 0.f, s1 = 0.f, s2 = 0.f, s3 = 0.f;
  float t0 = 0.f, t1 = 0.f, t2 = 0.f, t3 = 0.f;
  int j = b;
  for (; j + 8 <= e; j += 8) {
    int a0 = csr[j],     a1 = csr[j + 1], a2 = csr[j + 2], a3 = csr[j + 3];
    int a4 = csr[j + 4], a5 = csr[j + 5], a6 = csr[j + 6], a7 = csr[j + 7];
    uint u0 = *(const uint*)(P8 + (size_t)a0 * 256 + 4 * lane);
    uint u1 = *(const uint*)(P8 + (size_t)a1 * 256 + 4 * lane);
    uint u2 = *(const uint*)(P8 + (size_t)a2 * 256 + 4 * lane);
    uint u3 = *(const uint*)(P8 + (size_t)a3 * 256 + 4 * lane);
    uint u4 = *(const uint*)(P8 + (size_t)a4 * 256 + 4 * lane);
    uint u5 = *(const uint*)(P8 + (size_t)a5 * 256 + 4 * lane);
    uint u6 = *(const uint*)(P8 + (size_t)a6 * 256 + 4 * lane);
    uint u7 = *(const uint*)(P8 + (size_t)a7 * 256 + 4 * lane);
    s0 += dec8_0(u0) + dec8_0(u1) + dec8_0(u2) + dec8_0(u3);
    s1 += dec8_1(u0) + dec8_1(u1) + dec8_1(u2) + dec8_1(u3);
    s2 += dec8_2(u0) + dec8_2(u1) + dec8_2(u2) + dec8_2(u3);
    s3 += dec8_3(u0) + dec8_3(u1) + dec8_3(u2) + dec8_3(u3);
    t0 += dec8_0(u4) + dec8_0(u5) + dec8_0(u6) + dec8_0(u7);
    t1 += dec8_1(u4) + dec8_1(u5) + dec8_1(u6) + dec8_1(u7);
    t2 += dec8_2(u4) + dec8_2(u5) + dec8_2(u6) + dec8_2(u7);
    t3 += dec8_3(u4) + dec8_3(u5) + dec8_3(u6) + dec8_3(u7);
  }
  if (j + 4 <= e) {
    int a0 = csr[j], a1 = csr[j + 1], a2 = csr[j + 2], a3 = csr[j + 3];
    uint u0 = *(const uint*)(P8 + (size_t)a0 * 256 + 4 * lane);
    uint u1 = *(const uint*)(P8 + (size_t)a1 * 256 + 4 * lane);
    uint u2 = *(const uint*)(P8 + (size_t)a2 * 256 + 4 * lane);
    uint u3 = *(const uint*)(P8 + (size_t)a3 * 256 + 4 * lane);
    s0 += dec8_0(u0) + dec8_0(u1) + dec8_0(u2) + dec8_0(u3);
    s1 += dec8_1(u0) + dec8_1(u1) + dec8_1(u2) + dec8_1(u3);
    s2 += dec8_2(u0) + dec8_2(u1) + dec8_2(u2) + dec8_2(u3);
    s3 += dec8_3(u0) + dec8_3(u1) + dec8_3(u2) + dec8_3(u3);
    j += 4;
  }
  for (; j < e; ++j) {
    uint u0 = *(const uint*)(P8 + (size_t)csr[j] * 256 + 4 * lane);
    s0 += dec8_0(u0);
    s1 += dec8_1(u0);
    s2 += dec8_2(u0);
    s3 += dec8_3(u0);
  }
  s0 += t0; s1 += t1; s2 += t2; s3 += t3;
  // cross-half exchange: low lanes get delta sums, high lanes get clean sums
  float o0 = __shfl_xor(s0, 32, 64);
  float o1 = __shfl_xor(s1, 32, 64);
  float o2 = __shfl_xor(s2, 32, 64);
  float o3 = __shfl_xor(s3, 32, 64);
  bool hi = lane >= 32;                       // hi half -> noisy branch
  float m0 = hi ? (s0 + o0) : s0;             // noisy = clean + delta
  float m1 = hi ? (s1 + o1) : s1;
  float m2 = hi ? (s2 + o2) : s2;
  float m3 = hi ? (s3 + o3) : s3;
  float invd = 1.f / (float)max(e - b, 1);
  // R2 row [2][128] f32: byte offset 16*lane spans clean(0-31)/noisy(32-63)
  float4 rv = *(const float4*)(R2 + (size_t)node * 256 + 4 * lane);
  float4 bb = *(const float4*)(bias + 4 * lq);
  float q0 = fmaxf(m0 * invd + bb.x + rv.x, 0.f);
  float q1 = fmaxf(m1 * invd + bb.y + rv.y, 0.f);
  float q2 = fmaxf(m2 * invd + bb.z + rv.z, 0.f);
  float q3 = fmaxf(m3 * invd + bb.w + rv.w, 0.f);
  size_t arow = (size_t)(2 * node + (hi ? 1 : 0)) * 128 + 4 * lq;
  ushort4 pk;
  pk.x = f2b(q0); pk.y = f2b(q1); pk.z = f2b(q2); pk.w = f2b(q3);
  *(ushort4*)(bout + arow) = pk;
  if (WF32) {
    float* dst = (hi ? f1 : f0) + (size_t)node * 128 + 4 * lq;
    *(float4*)dst = make_float4(q0, q1, q2, q3);
  }
}

// layer 2: clean bf16 Pzc[node][64] (1 line) + fp8 delta Pzd[node][64]
// (64 B, 3.2 MB table ~L2-resident). 1 wave/node, col = lane; both branches
// per lane; fused log_softmax per branch over 47 lanes.
__global__ __launch_bounds__(256) void agg47_dual(
    const ushort* __restrict__ Pzc, const uchar* __restrict__ Pzd,
    const float* __restrict__ Rz, const float* __restrict__ bias,
    const int* __restrict__ off, const int* __restrict__ csr,
    float* __restrict__ z0, float* __restrict__ z1, float* __restrict__ y0,
    float* __restrict__ y1, int N) {
  int node = (blockIdx.x * blockDim.x + threadIdx.x) >> 6;
  int lane = threadIdx.x & 63;
  if (node >= N) return;
  int lq = lane & 31;
  int b = off[node], e = off[node + 1];
  float a = 0.f, aa = 0.f;      // clean sum, col = lane
  float g0 = 0.f, g1 = 0.f;     // delta sums, cols 2lq, 2lq+1 (dup on hi half)
  float h0 = 0.f, h1 = 0.f;
  int j = b;
  for (; j + 8 <= e; j += 8) {
    int a0 = csr[j],     a1 = csr[j + 1], a2 = csr[j + 2], a3 = csr[j + 3];
    int a4 = csr[j + 4], a5 = csr[j + 5], a6 = csr[j + 6], a7 = csr[j + 7];
    uint c0 = Pzc[(size_t)a0 * 64 + lane];
    uint c1 = Pzc[(size_t)a1 * 64 + lane];
    uint c2 = Pzc[(size_t)a2 * 64 + lane];
    uint c3 = Pzc[(size_t)a3 * 64 + lane];
    uint c4 = Pzc[(size_t)a4 * 64 + lane];
    uint c5 = Pzc[(size_t)a5 * 64 + lane];
    uint c6 = Pzc[(size_t)a6 * 64 + lane];
    uint c7 = Pzc[(size_t)a7 * 64 + lane];
    uint d0 = *(const ushort*)(Pzd + (size_t)a0 * 64 + 2 * lq);
    uint d1 = *(const ushort*)(Pzd + (size_t)a1 * 64 + 2 * lq);
    uint d2 = *(const ushort*)(Pzd + (size_t)a2 * 64 + 2 * lq);
    uint d3 = *(const ushort*)(Pzd + (size_t)a3 * 64 + 2 * lq);
    uint d4 = *(const ushort*)(Pzd + (size_t)a4 * 64 + 2 * lq);
    uint d5 = *(const ushort*)(Pzd + (size_t)a5 * 64 + 2 * lq);
    uint d6 = *(const ushort*)(Pzd + (size_t)a6 * 64 + 2 * lq);
    uint d7 = *(const ushort*)(Pzd + (size_t)a7 * 64 + 2 * lq);
    a  += b2f_lo(c0) + b2f_lo(c1) + b2f_lo(c2) + b2f_lo(c3);
    aa += b2f_lo(c4) + b2f_lo(c5) + b2f_lo(c6) + b2f_lo(c7);
    g0 += dec8_0(d0) + dec8_0(d1) + dec8_0(d2) + dec8_0(d3);
    g1 += dec8_1(d0) + dec8_1(d1) + dec8_1(d2) + dec8_1(d3);
    h0 += dec8_0(d4) + dec8_0(d5) + dec8_0(d6) + dec8_0(d7);
    h1 += dec8_1(d4) + dec8_1(d5) + dec8_1(d6) + dec8_1(d7);
  }
  if (j + 4 <= e) {
    int a0 = csr[j], a1 = csr[j + 1], a2 = csr[j + 2], a3 = csr[j + 3];
    uint c0 = Pzc[(size_t)a0 * 64 + lane];
    uint c1 = Pzc[(size_t)a1 * 64 + lane];
    uint c2 = Pzc[(size_t)a2 * 64 + lane];
    uint c3 = Pzc[(size_t)a3 * 64 + lane];
    uint d0 = *(const ushort*)(Pzd + (size_t)a0 * 64 + 2 * lq);
    uint d1 = *(const ushort*)(Pzd + (size_t)a1 * 64 + 2 * lq);
    uint d2 = *(const ushort*)(Pzd + (size_t)a2 * 64 + 2 * lq);
    uint d3 = *(const ushort*)(Pzd + (size_t)a3 * 64 + 2 * lq);
    a  += b2f_lo(c0) + b2f_lo(c1) + b2f_lo(c2) + b2f_lo(c3);
    g0 += dec8_0(d0) + dec8_0(d1) + dec8_0(d2) + dec8_0(d3);
    g1 += dec8_1(d0) + dec8_1(d1) + dec8_1(d2) + dec8_1(d3);
    j += 4;
  }
  for (; j < e; ++j) {
    uint c0 = Pzc[(size_t)csr[j] * 64 + lane];
    uint d0 = *(const ushort*)(Pzd + (size_t)csr[j] * 64 + 2 * lq);
    a += b2f_lo(c0);
    g0 += dec8_0(d0);
    g1 += dec8_1(d0);
  }
  a += aa; g0 += h0; g1 += h1;
  // delta for col = lane lives on lane>>1 (component lane&1)
  float dd0 = __shfl(g0, lane >> 1, 64);
  float dd1 = __shfl(g1, lane >> 1, 64);
  float dl = (lane & 1) ? dd1 : dd0;
  bool v = lane < 47;
  float invd = 1.f / (float)max(e - b, 1);
  float rc = Rz[(size_t)node * 128 + lane];        // cols 47..63: pad, masked
  float rn = Rz[(size_t)node * 128 + 64 + lane];
  float bl = v ? bias[lane] : 0.f;
  float za = v ? (a * invd + bl + rc) : -INFINITY;
  float zn = v ? ((a + dl) * invd + bl + rn) : -INFINITY;
  float ma = za, mb = zn;
#pragma unroll
  for (int d = 1; d < 64; d <<= 1) {
    ma = fmaxf(ma, __shfl_xor(ma, d, 64));
    mb = fmaxf(mb, __shfl_xor(mb, d, 64));
  }
  float sa = v ? __expf(za - ma) : 0.f;
  float sb = v ? __expf(zn - mb) : 0.f;
#pragma unroll
  for (int d = 1; d < 64; d <<= 1) {
    sa += __shfl_xor(sa, d, 64);
    sb += __shfl_xor(sb, d, 64);
  }
  float lsa = logf(sa) + ma;
  float lsb = logf(sb) + mb;
  if (v) {
    z0[(size_t)node * 47 + lane] = za;
    y0[(size_t)node * 47 + lane] = za - lsa;
    z1[(size_t)node * 47 + lane] = zn;
    y1[(size_t)node * 47 + lane] = zn - lsb;
  }
}

// ---------------------------------------------------------------------------
extern "C" void kernel_launch(void* const* d_in, const int* in_sizes, int n_in,
                              void* d_out, int out_size, void* d_ws,
                              size_t ws_size, hipStream_t stream) {
  const float* x = (const float*)d_in[0];
  const int* ei = (const int*)d_in[1];
  const float* noise = (const float*)d_in[2];
  const float* Wl0 = (const float*)d_in[3];
  const float* bl0 = (const float*)d_in[4];
  const float* Wr0 = (const float*)d_in[5];
  const float* Wl1 = (const float*)d_in[6];
  const float* bl1 = (const float*)d_in[7];
  const float* Wr1 = (const float*)d_in[8];
  const float* Wl2 = (const float*)d_in[9];
  const float* bl2 = (const float*)d_in[10];
  const float* Wr2 = (const float*)d_in[11];

  const int N = in_sizes[0] / 128;
  const int E = in_sizes[1] / 2;
  const int M = 2 * N;

  float* out = (float*)d_out;
  float* h_p = out;
  float* y_p = h_p + (size_t)N * 128;
  float* z_p = y_p + (size_t)N * 47;
  float* h_n = z_p + (size_t)N * 47;
  float* y_n = h_n + (size_t)N * 128;
  float* z_n = y_n + (size_t)N * 47;

  char* w = (char*)d_ws;
  auto alloc = [&](size_t bytes) {
    void* p = (void*)w;
    w += (bytes + 511) & ~(size_t)511;
    return p;
  };
  ushort* XB = (ushort*)alloc((size_t)M * 128 * 2);   // bf16 [M][128] interleaved
  uchar* P8 = (uchar*)alloc((size_t)N * 256);         // fp8 clean|delta rows
  float* Rf = (float*)alloc((size_t)M * 128 * 4);     // R / Rz
  ushort* WB0 = (ushort*)alloc(256 * 128 * 2);
  ushort* WB1 = (ushort*)alloc(256 * 128 * 2);
  ushort* WB2 = (ushort*)alloc(94 * 128 * 2);
  int* cnt = (int*)alloc((size_t)N * 4);
  int* off = (int*)alloc((size_t)(N + 1) * 4);
  int* rank = (int*)alloc((size_t)E * 4);
  int* loc = (int*)alloc((size_t)N * 4);
  int* bsum = (int*)alloc((size_t)256 * 4);
  int* csr = (int*)alloc((size_t)E * 4);
  // layer-2 tables carved from P8 region (N*128 B + N*64 B <= N*256 B)
  ushort* Pzc = (ushort*)P8;
  uchar* Pzd = P8 + (size_t)N * 128;

  conv_weights<<<(16384 + 255) / 256, 256, 0, stream>>>(
      Wl0, Wr0, Wl1, Wr1, Wl2, Wr2, WB0, WB1, WB2);

  // CSR build (rank-based: fill has no atomics)
  hipMemsetAsync(cnt, 0, (size_t)N * 4, stream);
  int eb = (E + 255) / 256;
  count_kernel<<<eb, 256, 0, stream>>>(ei + E, cnt, rank, E);
  int sb = (N + 1023) / 1024;
  scan_blocks<<<sb, 256, 0, stream>>>(cnt, loc, bsum, N);
  scan_bsums<<<1, 256, 0, stream>>>(bsum, sb);
  scan_apply<<<(N + 255) / 256, 256, 0, stream>>>(loc, bsum, off, N, E);
  fill_kernel<<<eb, 256, 0, stream>>>(ei, ei + E, rank, off, csr, E);

  int nwb = (N + 3) / 4;       // 1 wave/node
  int rb = (M + 127) / 128;    // GEMM row blocks

  noisy_convert<<<nwb, 256, 0, stream>>>(x, noise, XB, N);

  // layer 0
  gemm_fused<<<rb, 512, 0, stream>>>(XB, WB0, P8, Rf, M);
  agg_dual128<false><<<nwb, 256, 0, stream>>>(P8, Rf, bl0, off, csr, nullptr,
                                              nullptr, XB, N);
  // layer 1 (h outputs + bf16 for next layer)
  gemm_fused<<<rb, 512, 0, stream>>>(XB, WB1, P8, Rf, M);
  agg_dual128<true><<<nwb, 256, 0, stream>>>(P8, Rf, bl1, off, csr, h_p, h_n,
                                             XB, N);
  // layer 2 + fused log_softmax
  gemm_l2<<<rb, 256, 0, stream>>>(XB, WB2, Pzc, Pzd, Rf, M);
  agg47_dual<<<nwb, 256, 0, stream>>>(Pzc, Pzd, Rf, bl2, off, csr, z_p, z_n,
                                      y_p, y_n, N);
}